// Round 1
// baseline (44.259 us; speedup 1.0000x reference)
//
#include <hip/hip_runtime.h>

#ifndef FLT_MAX
#define FLT_MAX 3.402823466e+38f
#endif

__device__ __forceinline__ float sel3(int i, float a, float b, float c) {
    return i == 0 ? a : (i == 1 ? b : c);
}

// One 64-lane wave per edge; 4 edges per 256-thread block.
__global__ __launch_bounds__(256) void clustgeo_edge_kernel(
    const float* __restrict__ data,    // (N,4) f32; coords = cols 1..3
    const int*   __restrict__ clusts,  // (C,64) int (harness-converted from i64)
    const int*   __restrict__ eidx,    // (2,E)  int
    float*       __restrict__ out,     // (E,19) f32
    int E)
{
    const int wave = threadIdx.x >> 6;
    const int lane = threadIdx.x & 63;
    const int e = blockIdx.x * 4 + wave;

    __shared__ float s_x2[4][64][3];

    float x1x = 0.f, x1y = 0.f, x1z = 0.f;
    const bool active = (e < E);
    if (active) {
        const int a = eidx[e];
        const int b = eidx[E + e];
        const int p1 = clusts[a * 64 + lane];
        const int p2 = clusts[b * 64 + lane];
        const float4 r1 = *reinterpret_cast<const float4*>(data + (size_t)p1 * 4);
        const float4 r2 = *reinterpret_cast<const float4*>(data + (size_t)p2 * 4);
        x1x = r1.y; x1y = r1.z; x1z = r1.w;
        s_x2[wave][lane][0] = r2.y;
        s_x2[wave][lane][1] = r2.z;
        s_x2[wave][lane][2] = r2.w;
    }
    __syncthreads();
    if (!active) return;

    // Per-lane scan over j: strict < keeps the FIRST minimum (numpy argmin).
    // __f*_rn intrinsics pin exact f32 mul/add order (no FMA contraction) so
    // near-ties resolve identically to the numpy reference.
    float best = FLT_MAX;
    int bj = 0;
    #pragma unroll
    for (int j = 0; j < 64; ++j) {
        const float dx = __fsub_rn(x1x, s_x2[wave][j][0]);
        const float dy = __fsub_rn(x1y, s_x2[wave][j][1]);
        const float dz = __fsub_rn(x1z, s_x2[wave][j][2]);
        const float d2 = __fadd_rn(__fadd_rn(__fmul_rn(dx, dx), __fmul_rn(dy, dy)),
                                   __fmul_rn(dz, dz));
        if (d2 < best) { best = d2; bj = j; }
    }
    int idx = (lane << 6) | bj;  // flattened i*64+j (i-major, matches reshape)

    // 64-lane butterfly reduce: min value, ties -> lowest flattened index.
    #pragma unroll
    for (int off = 32; off > 0; off >>= 1) {
        const float ov = __shfl_xor(best, off, 64);
        const int   oi = __shfl_xor(idx,  off, 64);
        if (ov < best || (ov == best && oi < idx)) { best = ov; idx = oi; }
    }

    const int i1 = idx >> 6;
    const int i2 = idx & 63;
    const float v1x = __shfl(x1x, i1, 64);
    const float v1y = __shfl(x1y, i1, 64);
    const float v1z = __shfl(x1z, i1, 64);
    const float v2x = s_x2[wave][i2][0];
    const float v2y = s_x2[wave][i2][1];
    const float v2z = s_x2[wave][i2][2];

    float dx = v1x - v2x, dy = v1y - v2y, dz = v1z - v2z;
    const float lend = sqrtf(dx * dx + dy * dy + dz * dz);
    if (lend > 0.f) { dx /= lend; dy /= lend; dz /= lend; }

    if (lane < 19) {
        float o;
        if (lane < 3)       o = sel3(lane,     v1x, v1y, v1z);
        else if (lane < 6)  o = sel3(lane - 3, v2x, v2y, v2z);
        else if (lane < 9)  o = sel3(lane - 6, dx, dy, dz);
        else if (lane == 9) o = lend;
        else {
            const int k = lane - 10;
            o = sel3(k / 3, dx, dy, dz) * sel3(k % 3, dx, dy, dz);
        }
        out[(size_t)e * 19 + lane] = o;
    }
}

extern "C" void kernel_launch(void* const* d_in, const int* in_sizes, int n_in,
                              void* d_out, int out_size, void* d_ws, size_t ws_size,
                              hipStream_t stream) {
    const float* data   = (const float*)d_in[0];
    const int*   clusts = (const int*)d_in[1];
    const int*   eidx   = (const int*)d_in[2];
    float*       out    = (float*)d_out;
    const int E = in_sizes[2] / 2;           // edge_index is (2, E)
    const int blocks = (E + 3) / 4;          // 4 edges (waves) per block
    clustgeo_edge_kernel<<<blocks, 256, 0, stream>>>(data, clusts, eidx, out, E);
}